// Round 6
// baseline (5272.309 us; speedup 1.0000x reference)
//
#include <hip/hip_runtime.h>
#include <hip/hip_bf16.h>
#include <hip/hip_fp16.h>
#include <math.h>

#define L 4096
#define D 512
#define PP 64
#define HH 128
#define EPSF 1e-8f

typedef _Float16 half2v __attribute__((ext_vector_type(2)));

__device__ __forceinline__ float dot2f(uint32_t a, uint32_t b, float c) {
#if __has_builtin(__builtin_amdgcn_fdot2)
  return __builtin_amdgcn_fdot2(__builtin_bit_cast(half2v, a),
                                __builtin_bit_cast(half2v, b), c, false);
#else
  half2v x = __builtin_bit_cast(half2v, a);
  half2v y = __builtin_bit_cast(half2v, b);
  c = fmaf((float)x[0], (float)y[0], c);
  c = fmaf((float)x[1], (float)y[1], c);
  return c;
#endif
}

// ---------------- norms: ||p_l||, ||h_l|| ----------------
__global__ __launch_bounds__(64) void norms_kernel(const float* __restrict__ fp, const float* __restrict__ fh,
                                                   float* __restrict__ np_, float* __restrict__ nh_) {
  int b = blockIdx.x;
  int which = b >> 12;
  int l = b & (L - 1);
  const float* v = (which ? fh : fp) + (size_t)l * D;
  float s = 0.f;
  for (int i = threadIdx.x; i < D; i += 64) { float x = v[i]; s += x * x; }
  for (int off = 32; off > 0; off >>= 1) s += __shfl_down(s, off);
  if (threadIdx.x == 0) (which ? nh_ : np_)[l] = sqrtf(s);
}

// ---------------- att = (p @ h^T) / clamp(np*nh) ----------------
__global__ __launch_bounds__(256) void att_kernel(const float* __restrict__ A, const float* __restrict__ B,
                                                  const float* __restrict__ np_, const float* __restrict__ nh_,
                                                  float* __restrict__ att) {
  __shared__ float As[64][33];
  __shared__ float Bs[64][33];
  const int t = threadIdx.x;
  const int tc = t & 15, tr = t >> 4;
  const int row0 = blockIdx.y * 64, col0 = blockIdx.x * 64;
  float acc[4][4] = {};
  for (int k0 = 0; k0 < D; k0 += 32) {
#pragma unroll
    for (int i = 0; i < 2; i++) {
      int idx = t + i * 256;            // float4 idx in [0,512)
      int r = idx >> 3, c4 = idx & 7;
      float4 va = *reinterpret_cast<const float4*>(&A[(size_t)(row0 + r) * D + k0 + c4 * 4]);
      float4 vb = *reinterpret_cast<const float4*>(&B[(size_t)(col0 + r) * D + k0 + c4 * 4]);
      As[r][c4 * 4 + 0] = va.x; As[r][c4 * 4 + 1] = va.y; As[r][c4 * 4 + 2] = va.z; As[r][c4 * 4 + 3] = va.w;
      Bs[r][c4 * 4 + 0] = vb.x; Bs[r][c4 * 4 + 1] = vb.y; Bs[r][c4 * 4 + 2] = vb.z; Bs[r][c4 * 4 + 3] = vb.w;
    }
    __syncthreads();
#pragma unroll
    for (int kk = 0; kk < 32; kk++) {
      float a[4], bb[4];
#pragma unroll
      for (int i = 0; i < 4; i++) a[i] = As[tr * 4 + i][kk];
#pragma unroll
      for (int j = 0; j < 4; j++) bb[j] = Bs[tc * 4 + j][kk];
#pragma unroll
      for (int i = 0; i < 4; i++)
#pragma unroll
        for (int j = 0; j < 4; j++) acc[i][j] += a[i] * bb[j];
    }
    __syncthreads();
  }
#pragma unroll
  for (int i = 0; i < 4; i++) {
    int l = row0 + tr * 4 + i;
    float npl = np_[l];
#pragma unroll
    for (int j = 0; j < 4; j++) {
      int cjj = col0 + tc * 4 + j;
      float den = npl * nh_[cjj];
      den = den > EPSF ? den : EPSF;
      att[(size_t)l * L + cjj] = acc[i][j] / den;
    }
  }
}

// ---------------- row sums of att ----------------
__global__ __launch_bounds__(256) void rowsum_kernel(const float* __restrict__ att, float* __restrict__ rs) {
  int row = blockIdx.x;
  float s = 0.f;
  for (int c = threadIdx.x; c < L; c += 256) s += att[(size_t)row * L + c];
  for (int off = 32; off > 0; off >>= 1) s += __shfl_down(s, off);
  __shared__ float ps[4];
  if ((threadIdx.x & 63) == 0) ps[threadIdx.x >> 6] = s;
  __syncthreads();
  if (threadIdx.x == 0) rs[row] = ps[0] + ps[1] + ps[2] + ps[3];
}

// ---------------- column sums of att (2-stage, deterministic) ----------------
__global__ __launch_bounds__(256) void colpart_kernel(const float* __restrict__ att, float* __restrict__ pr) {
  int bx = blockIdx.x & 15, by = blockIdx.x >> 4;
  int col = bx * 256 + threadIdx.x;
  int r0 = by * 64;
  float s = 0.f;
#pragma unroll 8
  for (int r = 0; r < 64; r++) s += att[(size_t)(r0 + r) * L + col];
  pr[(size_t)by * L + col] = s;
}
__global__ __launch_bounds__(256) void colsum_kernel(const float* __restrict__ pr, float* __restrict__ cs) {
  int col = blockIdx.x * 256 + threadIdx.x;
  float s = 0.f;
#pragma unroll 8
  for (int k = 0; k < 64; k++) s += pr[(size_t)k * L + col];
  cs[col] = s;
}

// ---------------- att_mean_h = (att @ h) / clamp(rs) ----------------
__global__ __launch_bounds__(256) void amh_kernel(const float* __restrict__ att, const float* __restrict__ B,
                                                  const float* __restrict__ rs, float* __restrict__ outm) {
  __shared__ float As[64][33];
  __shared__ float Bs[32][65];
  const int t = threadIdx.x;
  const int tc = t & 15, tr = t >> 4;
  const int row0 = blockIdx.y * 64, col0 = blockIdx.x * 64;
  float acc[4][4] = {};
  for (int k0 = 0; k0 < L; k0 += 32) {
#pragma unroll
    for (int i = 0; i < 2; i++) {
      int idx = t + i * 256;
      int r = idx >> 3, c4 = idx & 7;
      float4 va = *reinterpret_cast<const float4*>(&att[(size_t)(row0 + r) * L + k0 + c4 * 4]);
      As[r][c4 * 4 + 0] = va.x; As[r][c4 * 4 + 1] = va.y; As[r][c4 * 4 + 2] = va.z; As[r][c4 * 4 + 3] = va.w;
      int rb = idx >> 4, cb4 = idx & 15;
      float4 vb = *reinterpret_cast<const float4*>(&B[(size_t)(k0 + rb) * D + col0 + cb4 * 4]);
      Bs[rb][cb4 * 4 + 0] = vb.x; Bs[rb][cb4 * 4 + 1] = vb.y; Bs[rb][cb4 * 4 + 2] = vb.z; Bs[rb][cb4 * 4 + 3] = vb.w;
    }
    __syncthreads();
#pragma unroll
    for (int kk = 0; kk < 32; kk++) {
      float a[4], bb[4];
#pragma unroll
      for (int i = 0; i < 4; i++) a[i] = As[tr * 4 + i][kk];
#pragma unroll
      for (int j = 0; j < 4; j++) bb[j] = Bs[kk][tc * 4 + j];
#pragma unroll
      for (int i = 0; i < 4; i++)
#pragma unroll
        for (int j = 0; j < 4; j++) acc[i][j] += a[i] * bb[j];
    }
    __syncthreads();
  }
#pragma unroll
  for (int i = 0; i < 4; i++) {
    int l = row0 + tr * 4 + i;
    float den = rs[l];
    den = den > EPSF ? den : EPSF;
#pragma unroll
    for (int j = 0; j < 4; j++)
      outm[(size_t)l * D + col0 + tc * 4 + j] = acc[i][j] / den;
  }
}

// ---------------- att_mean_p = (att^T @ p) / clamp(cs) ----------------
__global__ __launch_bounds__(256) void amp_kernel(const float* __restrict__ att, const float* __restrict__ B,
                                                  const float* __restrict__ cs, float* __restrict__ outm) {
  __shared__ float As[64][33];
  __shared__ float Bs[32][65];
  const int t = threadIdx.x;
  const int tc = t & 15, tr = t >> 4;
  const int row0 = blockIdx.y * 64, col0 = blockIdx.x * 64;
  float acc[4][4] = {};
  for (int k0 = 0; k0 < L; k0 += 32) {
#pragma unroll
    for (int i = 0; i < 8; i++) {
      int idx = t + i * 256;          // 2048 scalars, coalesced in 64-wide groups
      int k = idx >> 6, jj = idx & 63;
      As[jj][k] = att[(size_t)(k0 + k) * L + row0 + jj];
    }
#pragma unroll
    for (int i = 0; i < 2; i++) {
      int idx = t + i * 256;
      int rb = idx >> 4, cb4 = idx & 15;
      float4 vb = *reinterpret_cast<const float4*>(&B[(size_t)(k0 + rb) * D + col0 + cb4 * 4]);
      Bs[rb][cb4 * 4 + 0] = vb.x; Bs[rb][cb4 * 4 + 1] = vb.y; Bs[rb][cb4 * 4 + 2] = vb.z; Bs[rb][cb4 * 4 + 3] = vb.w;
    }
    __syncthreads();
#pragma unroll
    for (int kk = 0; kk < 32; kk++) {
      float a[4], bb[4];
#pragma unroll
      for (int i = 0; i < 4; i++) a[i] = As[tr * 4 + i][kk];
#pragma unroll
      for (int j = 0; j < 4; j++) bb[j] = Bs[kk][tc * 4 + j];
#pragma unroll
      for (int i = 0; i < 4; i++)
#pragma unroll
        for (int j = 0; j < 4; j++) acc[i][j] += a[i] * bb[j];
    }
    __syncthreads();
  }
#pragma unroll
  for (int i = 0; i < 4; i++) {
    int jrow = row0 + tr * 4 + i;
    float den = cs[jrow];
    den = den > EPSF ? den : EPSF;
#pragma unroll
    for (int j = 0; j < 4; j++)
      outm[(size_t)jrow * D + col0 + tc * 4 + j] = acc[i][j] / den;
  }
}

// ---------------- w2 transposed: w2t[d][p] = mp_w[p][d]^2 ----------------
__global__ void w2t_kernel(const float* __restrict__ mpw, float* __restrict__ w2t) {
  int o = blockIdx.x * blockDim.x + threadIdx.x;
  if (o >= PP * D) return;
  int dd = o >> 6, p = o & 63;
  float v = mpw[(size_t)p * D + dd];
  w2t[o] = v * v;
}

// ---------------- multi-perspective weighted cosine ----------------
__global__ __launch_bounds__(64) void match_kernel(const float* __restrict__ fp, const float* __restrict__ fh,
                                                   const float* __restrict__ amh, const float* __restrict__ amp,
                                                   const float* __restrict__ w2t,
                                                   float* __restrict__ match_p, float* __restrict__ match_h) {
  int b = blockIdx.x;
  int which = b >> 12;
  int l = b & (L - 1);
  const float* v1 = (which ? fh : fp) + (size_t)l * D;
  const float* v2 = (which ? amp : amh) + (size_t)l * D;
  __shared__ float s1[D], s2[D];
  int t = threadIdx.x;
#pragma unroll
  for (int i = 0; i < 2; i++) {
    int f4 = t + 64 * i;
    *reinterpret_cast<float4*>(&s1[f4 * 4]) = *reinterpret_cast<const float4*>(&v1[f4 * 4]);
    *reinterpret_cast<float4*>(&s2[f4 * 4]) = *reinterpret_cast<const float4*>(&v2[f4 * 4]);
  }
  __syncthreads();
  float num = 0.f, a1 = 0.f, a2 = 0.f;
  for (int dd = 0; dd < D; dd++) {
    float wv = w2t[dd * PP + t];
    float x = s1[dd], y = s2[dd];
    num += wv * x * y;
    a1 += wv * x * x;
    a2 += wv * y * y;
  }
  float n1 = fmaxf(sqrtf(a1), EPSF), n2 = fmaxf(sqrtf(a2), EPSF);
  float* outm = which ? match_h : match_p;
  outm[(size_t)l * PP + t] = num / (n1 * n2);
}

// ---------------- gx = match @ w_ih^T + (b_ih + b_hh), time-reversed for odd dirs ----------------
__global__ __launch_bounds__(512) void gx_kernel(const float* __restrict__ match_p, const float* __restrict__ match_h,
                                                 const float* __restrict__ wih_f, const float* __restrict__ wih_r,
                                                 const float* __restrict__ bih_f, const float* __restrict__ bhh_f,
                                                 const float* __restrict__ bih_r, const float* __restrict__ bhh_r,
                                                 float* __restrict__ gx) {
  int b = blockIdx.x;
  int dir = b >> 9;
  int chunk = b & 511;
  const float* m_src = (dir < 2) ? match_p : match_h;
  const float* wih = (dir & 1) ? wih_r : wih_f;
  const float* bi = (dir & 1) ? bih_r : bih_f;
  const float* bh = (dir & 1) ? bhh_r : bhh_f;
  __shared__ float m[8][PP];
  int t = threadIdx.x;
  {
    int tt = t >> 6, p = t & 63;
    int tstep = chunk * 8 + tt;
    int row = (dir & 1) ? (L - 1 - tstep) : tstep;
    m[tt][p] = m_src[(size_t)row * PP + p];
  }
  __syncthreads();
  int j = t;
  float bias = bi[j] + bh[j];
  float acc[8];
#pragma unroll
  for (int tt = 0; tt < 8; tt++) acc[tt] = bias;
  for (int p = 0; p < PP; p++) {
    float wv = wih[(size_t)j * PP + p];
#pragma unroll
    for (int tt = 0; tt < 8; tt++) acc[tt] += wv * m[tt][p];
  }
#pragma unroll
  for (int tt = 0; tt < 8; tt++)
    gx[((size_t)dir * L + chunk * 8 + tt) * 512 + j] = acc[tt];
}

// ---------------- pack whh_f/whh_r to fp16 half2 words ----------------
// pk[o] for o<32768 covers whh_f, o>=32768 covers whh_r; word o&32767 holds
// halfs (2k,2k+1) of row j where (o&32767) = j*64 + k2 (k2 = k/2).
__global__ __launch_bounds__(256) void packw_kernel(const float* __restrict__ wf,
                                                    const float* __restrict__ wr,
                                                    uint32_t* __restrict__ pk) {
  int o = blockIdx.x * 256 + threadIdx.x;       // 65536 total
  const float* src = (o < 32768) ? wf : wr;
  int idx = (o & 32767) * 2;
  __half a = __float2half(src[idx]);
  __half b = __float2half(src[idx + 1]);
  pk[o] = (uint32_t)__half_as_ushort(a) | ((uint32_t)__half_as_ushort(b) << 16);
}

// ---------------- 4 sequential LSTMs (persistent blocks) ----------------
// ROUNDS 1-5 LESSON: at 512 threads the RA clamps to ~84 VGPR and remats the
// weight loads (256KB/step from L2 ~= 2000 cyc/step) no matter what asm pins
// are applied. Fix: make register DEMAND fit under the clamp instead of
// fighting it. 1024 threads (16 waves): 16-lane group owns 8 outputs; lane g
// holds k-segment [8g, 8g+8) of all 8 outputs as PACKED FP16 = 32 VGPRs.
// Recurrent matvec via v_dot2_f32_f16 (fp32 accumulate): 32 dot2/thread/step
// -> 64K MAC/step at 256 MAC/cyc/CU issue = 256 cyc/step floor.
// h is packed fp16 in LDS (256B): lane reads one 16B fragment (~2-way bank
// aliasing = free). Reduction: 3 compacting shuffles (xor 1,2,4) + xor 8.
// Precision: |w|<=0.09 -> fp16 weight rounding ~2e-4/gate; fp16 h ~5e-4/step
// into a contractive recurrence; threshold is 9.45e-3.
__global__ __attribute__((amdgpu_waves_per_eu(4, 4))) __launch_bounds__(1024)
void lstm_kernel(const float* __restrict__ gx, const uint32_t* __restrict__ pk,
                 float* __restrict__ out) {
  const int dir = blockIdx.x;
  const uint32_t* __restrict__ w = pk + (size_t)(dir & 1) * 32768;
  const int tid = threadIdx.x;
  const int g = tid & 15;                 // k-segment index within group
  const int jbase = (tid >> 4) << 3;      // first of this group's 8 outputs
  const int jmine = jbase | (tid & 7);    // the output this thread finalizes

  uint32_t wv[8][4];
#pragma unroll
  for (int jj = 0; jj < 8; jj++) {
    uint4 v = *reinterpret_cast<const uint4*>(&w[(size_t)(jbase + jj) * 64 + g * 4]);
    wv[jj][0] = v.x; wv[jj][1] = v.y; wv[jj][2] = v.z; wv[jj][3] = v.w;
  }

  __shared__ __align__(16) uint32_t h_pk[64];   // 128 halfs
  __shared__ float act[512];
  if (tid < 64) h_pk[tid] = 0u;
  __syncthreads();

  const float* __restrict__ gsrc = gx + (size_t)dir * L * 512;
  float gval = gsrc[jmine];
  const int m = tid & 127;
  const int is_g_gate = ((jmine >> 7) == 2);    // wave-uniform (32 j's/wave)
  const int b0 = tid & 1, b1 = tid & 2, b2 = tid & 4;
  float c = 0.f, h = 0.f;

  for (int t = 0; t < L; t++) {
    float gnext = (t + 1 < L) ? gsrc[(size_t)(t + 1) * 512 + jmine] : 0.f;
    uint4 hf = *reinterpret_cast<const uint4*>(&h_pk[g * 4]);
    float acc[8];
#pragma unroll
    for (int jj = 0; jj < 8; jj++) {
      float s0 = dot2f(wv[jj][0], hf.x, 0.f);
      float s1 = dot2f(wv[jj][1], hf.y, 0.f);
      s0 = dot2f(wv[jj][2], hf.z, s0);
      s1 = dot2f(wv[jj][3], hf.w, s1);
      acc[jj] = s0 + s1;
    }
    // compacting butterfly over the 8-lane window, then combine k-halves
    float r4[4];
#pragma unroll
    for (int i = 0; i < 4; i++) {
      float keep = b0 ? acc[2 * i + 1] : acc[2 * i];
      float send = b0 ? acc[2 * i] : acc[2 * i + 1];
      r4[i] = keep + __shfl_xor(send, 1);
    }
    float r2[2];
#pragma unroll
    for (int u = 0; u < 2; u++) {
      float keep = b1 ? r4[2 * u + 1] : r4[2 * u];
      float send = b1 ? r4[2 * u] : r4[2 * u + 1];
      r2[u] = keep + __shfl_xor(send, 2);
    }
    float keep1 = b2 ? r2[1] : r2[0];
    float send1 = b2 ? r2[0] : r2[1];
    float r1 = keep1 + __shfl_xor(send1, 4);
    float z = r1 + __shfl_xor(r1, 8) + gval;
    float a;
    if (is_g_gate) {
      float e = __expf(2.f * z);
      a = 1.f - 2.f / (e + 1.f);
    } else {
      a = 1.f / (1.f + __expf(-z));
    }
    act[jmine] = a;                       // lanes g and g+8 write same value
    __syncthreads();
    if (tid < HH) {                       // waves 0-1 only (wave-uniform)
      float iv = act[m], fv = act[HH + m], gg = act[2 * HH + m], ov = act[3 * HH + m];
      c = fv * c + iv * gg;
      float e2 = __expf(2.f * c);
      h = ov * (1.f - 2.f / (e2 + 1.f));
      reinterpret_cast<__half*>(h_pk)[m] = __float2half(h);
    }
    __syncthreads();
    gval = gnext;
  }
  if (tid < HH) out[dir * HH + tid] = h;
}

extern "C" void kernel_launch(void* const* d_in, const int* in_sizes, int n_in,
                              void* d_out, int out_size, void* d_ws, size_t ws_size,
                              hipStream_t stream) {
  const float* fp    = (const float*)d_in[0];
  const float* fh    = (const float*)d_in[1];
  const float* mpw   = (const float*)d_in[2];
  const float* wih_f = (const float*)d_in[3];
  const float* whh_f = (const float*)d_in[4];
  const float* bih_f = (const float*)d_in[5];
  const float* bhh_f = (const float*)d_in[6];
  const float* wih_r = (const float*)d_in[7];
  const float* whh_r = (const float*)d_in[8];
  const float* bih_r = (const float*)d_in[9];
  const float* bhh_r = (const float*)d_in[10];
  float* out = (float*)d_out;
  float* ws = (float*)d_ws;

  // workspace layout (floats)
  size_t np_off  = 0;                       // 4096
  size_t nh_off  = np_off + L;              // 4096
  size_t rs_off  = nh_off + L;              // 4096
  size_t cs_off  = rs_off + L;              // 4096
  size_t w2_off  = cs_off + L;              // 32768
  size_t amh_off = w2_off + (size_t)PP * D; // 2097152
  size_t amp_off = amh_off + (size_t)L * D; // 2097152
  size_t mp_off  = amp_off + (size_t)L * D; // 262144
  size_t mh_off  = mp_off + (size_t)L * PP; // 262144
  size_t pr_off  = mh_off + (size_t)L * PP; // 262144 (64 x 4096); pk aliases after colsum
  size_t att_off = pr_off + (size_t)64 * L; // 16777216
  size_t gx_off  = att_off;                 // alias: gx (8388608) reuses dead att region
  size_t total   = att_off + (size_t)L * L;
  if (ws_size < total * sizeof(float)) return;  // workspace too small — bail safely

  float* np_  = ws + np_off;
  float* nh_  = ws + nh_off;
  float* rs   = ws + rs_off;
  float* cs   = ws + cs_off;
  float* w2t  = ws + w2_off;
  float* amh  = ws + amh_off;
  float* amp  = ws + amp_off;
  float* mtp  = ws + mp_off;
  float* mth  = ws + mh_off;
  float* pr   = ws + pr_off;
  uint32_t* pk = (uint32_t*)(ws + pr_off);  // 65536 uint32 = 256KB, fits in pr's 1MB
  float* att  = ws + att_off;
  float* gx   = ws + gx_off;

  norms_kernel<<<2 * L, 64, 0, stream>>>(fp, fh, np_, nh_);
  att_kernel<<<dim3(64, 64), 256, 0, stream>>>(fp, fh, np_, nh_, att);
  rowsum_kernel<<<L, 256, 0, stream>>>(att, rs);
  colpart_kernel<<<1024, 256, 0, stream>>>(att, pr);
  colsum_kernel<<<16, 256, 0, stream>>>(pr, cs);
  packw_kernel<<<256, 256, 0, stream>>>(whh_f, whh_r, pk);   // pr dead after colsum
  amh_kernel<<<dim3(8, 64), 256, 0, stream>>>(att, fh, rs, amh);
  amp_kernel<<<dim3(8, 64), 256, 0, stream>>>(att, fp, cs, amp);
  w2t_kernel<<<(PP * D + 255) / 256, 256, 0, stream>>>(mpw, w2t);
  match_kernel<<<2 * L, 64, 0, stream>>>(fp, fh, amh, amp, w2t, mtp, mth);
  gx_kernel<<<4 * (L / 8), 512, 0, stream>>>(mtp, mth, wih_f, wih_r, bih_f, bhh_f, bih_r, bhh_r, gx);
  lstm_kernel<<<4, 1024, 0, stream>>>(gx, pk, out);
}

// Round 7
// 5231.538 us; speedup vs baseline: 1.0078x; 1.0078x over previous
//
#include <hip/hip_runtime.h>
#include <hip/hip_bf16.h>
#include <math.h>

#define L 4096
#define D 512
#define PP 64
#define HH 128
#define EPSF 1e-8f

// ---------------- norms: ||p_l||, ||h_l|| ----------------
__global__ __launch_bounds__(64) void norms_kernel(const float* __restrict__ fp, const float* __restrict__ fh,
                                                   float* __restrict__ np_, float* __restrict__ nh_) {
  int b = blockIdx.x;
  int which = b >> 12;
  int l = b & (L - 1);
  const float* v = (which ? fh : fp) + (size_t)l * D;
  float s = 0.f;
  for (int i = threadIdx.x; i < D; i += 64) { float x = v[i]; s += x * x; }
  for (int off = 32; off > 0; off >>= 1) s += __shfl_down(s, off);
  if (threadIdx.x == 0) (which ? nh_ : np_)[l] = sqrtf(s);
}

// ---------------- att = (p @ h^T) / clamp(np*nh) ----------------
__global__ __launch_bounds__(256) void att_kernel(const float* __restrict__ A, const float* __restrict__ B,
                                                  const float* __restrict__ np_, const float* __restrict__ nh_,
                                                  float* __restrict__ att) {
  __shared__ float As[64][33];
  __shared__ float Bs[64][33];
  const int t = threadIdx.x;
  const int tc = t & 15, tr = t >> 4;
  const int row0 = blockIdx.y * 64, col0 = blockIdx.x * 64;
  float acc[4][4] = {};
  for (int k0 = 0; k0 < D; k0 += 32) {
#pragma unroll
    for (int i = 0; i < 2; i++) {
      int idx = t + i * 256;            // float4 idx in [0,512)
      int r = idx >> 3, c4 = idx & 7;
      float4 va = *reinterpret_cast<const float4*>(&A[(size_t)(row0 + r) * D + k0 + c4 * 4]);
      float4 vb = *reinterpret_cast<const float4*>(&B[(size_t)(col0 + r) * D + k0 + c4 * 4]);
      As[r][c4 * 4 + 0] = va.x; As[r][c4 * 4 + 1] = va.y; As[r][c4 * 4 + 2] = va.z; As[r][c4 * 4 + 3] = va.w;
      Bs[r][c4 * 4 + 0] = vb.x; Bs[r][c4 * 4 + 1] = vb.y; Bs[r][c4 * 4 + 2] = vb.z; Bs[r][c4 * 4 + 3] = vb.w;
    }
    __syncthreads();
#pragma unroll
    for (int kk = 0; kk < 32; kk++) {
      float a[4], bb[4];
#pragma unroll
      for (int i = 0; i < 4; i++) a[i] = As[tr * 4 + i][kk];
#pragma unroll
      for (int j = 0; j < 4; j++) bb[j] = Bs[tc * 4 + j][kk];
#pragma unroll
      for (int i = 0; i < 4; i++)
#pragma unroll
        for (int j = 0; j < 4; j++) acc[i][j] += a[i] * bb[j];
    }
    __syncthreads();
  }
#pragma unroll
  for (int i = 0; i < 4; i++) {
    int l = row0 + tr * 4 + i;
    float npl = np_[l];
#pragma unroll
    for (int j = 0; j < 4; j++) {
      int cjj = col0 + tc * 4 + j;
      float den = npl * nh_[cjj];
      den = den > EPSF ? den : EPSF;
      att[(size_t)l * L + cjj] = acc[i][j] / den;
    }
  }
}

// ---------------- row sums of att ----------------
__global__ __launch_bounds__(256) void rowsum_kernel(const float* __restrict__ att, float* __restrict__ rs) {
  int row = blockIdx.x;
  float s = 0.f;
  for (int c = threadIdx.x; c < L; c += 256) s += att[(size_t)row * L + c];
  for (int off = 32; off > 0; off >>= 1) s += __shfl_down(s, off);
  __shared__ float ps[4];
  if ((threadIdx.x & 63) == 0) ps[threadIdx.x >> 6] = s;
  __syncthreads();
  if (threadIdx.x == 0) rs[row] = ps[0] + ps[1] + ps[2] + ps[3];
}

// ---------------- column sums of att (2-stage, deterministic) ----------------
__global__ __launch_bounds__(256) void colpart_kernel(const float* __restrict__ att, float* __restrict__ pr) {
  int bx = blockIdx.x & 15, by = blockIdx.x >> 4;
  int col = bx * 256 + threadIdx.x;
  int r0 = by * 64;
  float s = 0.f;
#pragma unroll 8
  for (int r = 0; r < 64; r++) s += att[(size_t)(r0 + r) * L + col];
  pr[(size_t)by * L + col] = s;
}
__global__ __launch_bounds__(256) void colsum_kernel(const float* __restrict__ pr, float* __restrict__ cs) {
  int col = blockIdx.x * 256 + threadIdx.x;
  float s = 0.f;
#pragma unroll 8
  for (int k = 0; k < 64; k++) s += pr[(size_t)k * L + col];
  cs[col] = s;
}

// ---------------- att_mean_h = (att @ h) / clamp(rs) ----------------
__global__ __launch_bounds__(256) void amh_kernel(const float* __restrict__ att, const float* __restrict__ B,
                                                  const float* __restrict__ rs, float* __restrict__ outm) {
  __shared__ float As[64][33];
  __shared__ float Bs[32][65];
  const int t = threadIdx.x;
  const int tc = t & 15, tr = t >> 4;
  const int row0 = blockIdx.y * 64, col0 = blockIdx.x * 64;
  float acc[4][4] = {};
  for (int k0 = 0; k0 < L; k0 += 32) {
#pragma unroll
    for (int i = 0; i < 2; i++) {
      int idx = t + i * 256;
      int r = idx >> 3, c4 = idx & 7;
      float4 va = *reinterpret_cast<const float4*>(&att[(size_t)(row0 + r) * L + k0 + c4 * 4]);
      As[r][c4 * 4 + 0] = va.x; As[r][c4 * 4 + 1] = va.y; As[r][c4 * 4 + 2] = va.z; As[r][c4 * 4 + 3] = va.w;
      int rb = idx >> 4, cb4 = idx & 15;
      float4 vb = *reinterpret_cast<const float4*>(&B[(size_t)(k0 + rb) * D + col0 + cb4 * 4]);
      Bs[rb][cb4 * 4 + 0] = vb.x; Bs[rb][cb4 * 4 + 1] = vb.y; Bs[rb][cb4 * 4 + 2] = vb.z; Bs[rb][cb4 * 4 + 3] = vb.w;
    }
    __syncthreads();
#pragma unroll
    for (int kk = 0; kk < 32; kk++) {
      float a[4], bb[4];
#pragma unroll
      for (int i = 0; i < 4; i++) a[i] = As[tr * 4 + i][kk];
#pragma unroll
      for (int j = 0; j < 4; j++) bb[j] = Bs[kk][tc * 4 + j];
#pragma unroll
      for (int i = 0; i < 4; i++)
#pragma unroll
        for (int j = 0; j < 4; j++) acc[i][j] += a[i] * bb[j];
    }
    __syncthreads();
  }
#pragma unroll
  for (int i = 0; i < 4; i++) {
    int l = row0 + tr * 4 + i;
    float den = rs[l];
    den = den > EPSF ? den : EPSF;
#pragma unroll
    for (int j = 0; j < 4; j++)
      outm[(size_t)l * D + col0 + tc * 4 + j] = acc[i][j] / den;
  }
}

// ---------------- att_mean_p = (att^T @ p) / clamp(cs) ----------------
__global__ __launch_bounds__(256) void amp_kernel(const float* __restrict__ att, const float* __restrict__ B,
                                                  const float* __restrict__ cs, float* __restrict__ outm) {
  __shared__ float As[64][33];
  __shared__ float Bs[32][65];
  const int t = threadIdx.x;
  const int tc = t & 15, tr = t >> 4;
  const int row0 = blockIdx.y * 64, col0 = blockIdx.x * 64;
  float acc[4][4] = {};
  for (int k0 = 0; k0 < L; k0 += 32) {
#pragma unroll
    for (int i = 0; i < 8; i++) {
      int idx = t + i * 256;          // 2048 scalars, coalesced in 64-wide groups
      int k = idx >> 6, jj = idx & 63;
      As[jj][k] = att[(size_t)(k0 + k) * L + row0 + jj];
    }
#pragma unroll
    for (int i = 0; i < 2; i++) {
      int idx = t + i * 256;
      int rb = idx >> 4, cb4 = idx & 15;
      float4 vb = *reinterpret_cast<const float4*>(&B[(size_t)(k0 + rb) * D + col0 + cb4 * 4]);
      Bs[rb][cb4 * 4 + 0] = vb.x; Bs[rb][cb4 * 4 + 1] = vb.y; Bs[rb][cb4 * 4 + 2] = vb.z; Bs[rb][cb4 * 4 + 3] = vb.w;
    }
    __syncthreads();
#pragma unroll
    for (int kk = 0; kk < 32; kk++) {
      float a[4], bb[4];
#pragma unroll
      for (int i = 0; i < 4; i++) a[i] = As[tr * 4 + i][kk];
#pragma unroll
      for (int j = 0; j < 4; j++) bb[j] = Bs[kk][tc * 4 + j];
#pragma unroll
      for (int i = 0; i < 4; i++)
#pragma unroll
        for (int j = 0; j < 4; j++) acc[i][j] += a[i] * bb[j];
    }
    __syncthreads();
  }
#pragma unroll
  for (int i = 0; i < 4; i++) {
    int jrow = row0 + tr * 4 + i;
    float den = cs[jrow];
    den = den > EPSF ? den : EPSF;
#pragma unroll
    for (int j = 0; j < 4; j++)
      outm[(size_t)jrow * D + col0 + tc * 4 + j] = acc[i][j] / den;
  }
}

// ---------------- w2 transposed: w2t[d][p] = mp_w[p][d]^2 ----------------
__global__ void w2t_kernel(const float* __restrict__ mpw, float* __restrict__ w2t) {
  int o = blockIdx.x * blockDim.x + threadIdx.x;
  if (o >= PP * D) return;
  int dd = o >> 6, p = o & 63;
  float v = mpw[(size_t)p * D + dd];
  w2t[o] = v * v;
}

// ---------------- multi-perspective weighted cosine ----------------
__global__ __launch_bounds__(64) void match_kernel(const float* __restrict__ fp, const float* __restrict__ fh,
                                                   const float* __restrict__ amh, const float* __restrict__ amp,
                                                   const float* __restrict__ w2t,
                                                   float* __restrict__ match_p, float* __restrict__ match_h) {
  int b = blockIdx.x;
  int which = b >> 12;
  int l = b & (L - 1);
  const float* v1 = (which ? fh : fp) + (size_t)l * D;
  const float* v2 = (which ? amp : amh) + (size_t)l * D;
  __shared__ float s1[D], s2[D];
  int t = threadIdx.x;
#pragma unroll
  for (int i = 0; i < 2; i++) {
    int f4 = t + 64 * i;
    *reinterpret_cast<float4*>(&s1[f4 * 4]) = *reinterpret_cast<const float4*>(&v1[f4 * 4]);
    *reinterpret_cast<float4*>(&s2[f4 * 4]) = *reinterpret_cast<const float4*>(&v2[f4 * 4]);
  }
  __syncthreads();
  float num = 0.f, a1 = 0.f, a2 = 0.f;
  for (int dd = 0; dd < D; dd++) {
    float wv = w2t[dd * PP + t];
    float x = s1[dd], y = s2[dd];
    num += wv * x * y;
    a1 += wv * x * x;
    a2 += wv * y * y;
  }
  float n1 = fmaxf(sqrtf(a1), EPSF), n2 = fmaxf(sqrtf(a2), EPSF);
  float* outm = which ? match_h : match_p;
  outm[(size_t)l * PP + t] = num / (n1 * n2);
}

// ---------------- gx = match @ w_ih^T + (b_ih + b_hh), time-reversed for odd dirs ----------------
__global__ __launch_bounds__(512) void gx_kernel(const float* __restrict__ match_p, const float* __restrict__ match_h,
                                                 const float* __restrict__ wih_f, const float* __restrict__ wih_r,
                                                 const float* __restrict__ bih_f, const float* __restrict__ bhh_f,
                                                 const float* __restrict__ bih_r, const float* __restrict__ bhh_r,
                                                 float* __restrict__ gx) {
  int b = blockIdx.x;
  int dir = b >> 9;
  int chunk = b & 511;
  const float* m_src = (dir < 2) ? match_p : match_h;
  const float* wih = (dir & 1) ? wih_r : wih_f;
  const float* bi = (dir & 1) ? bih_r : bih_f;
  const float* bh = (dir & 1) ? bhh_r : bhh_f;
  __shared__ float m[8][PP];
  int t = threadIdx.x;
  {
    int tt = t >> 6, p = t & 63;
    int tstep = chunk * 8 + tt;
    int row = (dir & 1) ? (L - 1 - tstep) : tstep;
    m[tt][p] = m_src[(size_t)row * PP + p];
  }
  __syncthreads();
  int j = t;
  float bias = bi[j] + bh[j];
  float acc[8];
#pragma unroll
  for (int tt = 0; tt < 8; tt++) acc[tt] = bias;
  for (int p = 0; p < PP; p++) {
    float wv = wih[(size_t)j * PP + p];
#pragma unroll
    for (int tt = 0; tt < 8; tt++) acc[tt] += wv * m[tt][p];
  }
#pragma unroll
  for (int tt = 0; tt < 8; tt++)
    gx[((size_t)dir * L + chunk * 8 + tt) * 512 + j] = acc[tt];
}

// ---------------- 4 sequential LSTMs (persistent blocks) ----------------
// ROUND-6 LESSON: demand-fits-budget works (VGPR=52, weights resident), but
// the packed-fp16 dot path SCALARIZED (no v_dot2 on gfx950 via builtin):
// ~1580 VALU cyc/step = 32 dot2-calls x (4 cvt + 2 fma). Fix: fp32 weights,
// same 1024-thread structure. 16-lane group owns 8 outputs; lane g holds
// k-seg [8g,8g+8) fp32 = 64 VGPR. At 1024 threads the flat-wg cap is
// 4 waves/EU -> RA budget 128 VGPR >= ~95 demand -> resident without pins.
// Matvec: 64 fma/thread -> 16 waves x 64 x 2cyc / 4 SIMD = 512 cyc/step
// (the fp32 floor for 64K MAC on one CU).
// h fp32 in 8-replica LDS (stride 132): lane g reads replica g&7 at word
// 132*(g&7)+8g -> (g,g+8) share a bank (2-way, free), groups broadcast.
// c/h update by ALL 1024 threads (redundant x8), each writes ONE replica
// slot -> no serial 2-wave phase. Reduction butterfly identical to r6
// (validated): xor1,2,4 compacting + xor8 k-half combine.
__global__ __attribute__((amdgpu_waves_per_eu(4, 4))) __launch_bounds__(1024)
void lstm_kernel(const float* __restrict__ gx,
                 const float* __restrict__ whh_f, const float* __restrict__ whh_r,
                 float* __restrict__ out) {
  const int dir = blockIdx.x;
  const float* __restrict__ whh = (dir & 1) ? whh_r : whh_f;
  const int tid = threadIdx.x;
  const int g = tid & 15;                 // k-segment index within group
  const int jbase = (tid >> 4) << 3;      // first of this group's 8 outputs
  const int jmine = jbase | (tid & 7);    // the output this thread finalizes

  float4 w4[8][2];
#pragma unroll
  for (int jj = 0; jj < 8; jj++) {
    w4[jj][0] = *reinterpret_cast<const float4*>(&whh[(size_t)(jbase + jj) * HH + g * 8]);
    w4[jj][1] = *reinterpret_cast<const float4*>(&whh[(size_t)(jbase + jj) * HH + g * 8 + 4]);
  }

  __shared__ __align__(16) float h_rep[8 * 132];   // 8 replicas, stride 132
  __shared__ float act[512];
  {
    int r = tid >> 7, mm = tid & 127;
    h_rep[r * 132 + mm] = 0.f;
  }
  __syncthreads();

  const float* __restrict__ gsrc = gx + (size_t)dir * L * 512;
  float gval = gsrc[jmine];
  const int m = tid & 127;
  const int rrep = tid >> 7;                    // replica slot this thread writes
  const int is_g_gate = ((jmine >> 7) == 2);    // wave-uniform
  const int b0 = tid & 1, b1 = tid & 2, b2 = tid & 4;
  const int hbase = (g & 7) * 132 + g * 8;      // replica g&7, fragment g
  float c = 0.f, h = 0.f;

  for (int t = 0; t < L; t++) {
    float gnext = (t + 1 < L) ? gsrc[(size_t)(t + 1) * 512 + jmine] : 0.f;
    float4 hf0 = *reinterpret_cast<const float4*>(&h_rep[hbase]);
    float4 hf1 = *reinterpret_cast<const float4*>(&h_rep[hbase + 4]);
    // 8 outputs x 8 k, all fp32, all operands in VGPRs
    float acc[8];
#pragma unroll
    for (int jj = 0; jj < 8; jj++) {
      float s0 = w4[jj][0].x * hf0.x;
      float s1 = w4[jj][0].y * hf0.y;
      s0 = fmaf(w4[jj][0].z, hf0.z, s0);
      s1 = fmaf(w4[jj][0].w, hf0.w, s1);
      s0 = fmaf(w4[jj][1].x, hf1.x, s0);
      s1 = fmaf(w4[jj][1].y, hf1.y, s1);
      s0 = fmaf(w4[jj][1].z, hf1.z, s0);
      s1 = fmaf(w4[jj][1].w, hf1.w, s1);
      acc[jj] = s0 + s1;
    }
    // compacting butterfly over the 8-lane window, then combine k-halves
    float r4[4];
#pragma unroll
    for (int i = 0; i < 4; i++) {
      float keep = b0 ? acc[2 * i + 1] : acc[2 * i];
      float send = b0 ? acc[2 * i] : acc[2 * i + 1];
      r4[i] = keep + __shfl_xor(send, 1);
    }
    float r2[2];
#pragma unroll
    for (int u = 0; u < 2; u++) {
      float keep = b1 ? r4[2 * u + 1] : r4[2 * u];
      float send = b1 ? r4[2 * u] : r4[2 * u + 1];
      r2[u] = keep + __shfl_xor(send, 2);
    }
    float keep1 = b2 ? r2[1] : r2[0];
    float send1 = b2 ? r2[0] : r2[1];
    float r1 = keep1 + __shfl_xor(send1, 4);
    float z = r1 + __shfl_xor(r1, 8) + gval;
    float a;
    if (is_g_gate) {
      float e = __expf(2.f * z);
      a = 1.f - 2.f / (e + 1.f);
    } else {
      a = 1.f / (1.f + __expf(-z));
    }
    act[jmine] = a;                       // dup pair writes same value
    __syncthreads();
    // c/h computed redundantly by all 1024 threads (c replicated x8 per m)
    float iv = act[m], fv = act[HH + m], gg = act[2 * HH + m], ov = act[3 * HH + m];
    c = fv * c + iv * gg;
    float e2 = __expf(2.f * c);
    h = ov * (1.f - 2.f / (e2 + 1.f));
    h_rep[rrep * 132 + m] = h;            // each thread fills one replica slot
    __syncthreads();
    gval = gnext;
  }
  if (tid < HH) out[dir * HH + tid] = h;
}

extern "C" void kernel_launch(void* const* d_in, const int* in_sizes, int n_in,
                              void* d_out, int out_size, void* d_ws, size_t ws_size,
                              hipStream_t stream) {
  const float* fp    = (const float*)d_in[0];
  const float* fh    = (const float*)d_in[1];
  const float* mpw   = (const float*)d_in[2];
  const float* wih_f = (const float*)d_in[3];
  const float* whh_f = (const float*)d_in[4];
  const float* bih_f = (const float*)d_in[5];
  const float* bhh_f = (const float*)d_in[6];
  const float* wih_r = (const float*)d_in[7];
  const float* whh_r = (const float*)d_in[8];
  const float* bih_r = (const float*)d_in[9];
  const float* bhh_r = (const float*)d_in[10];
  float* out = (float*)d_out;
  float* ws = (float*)d_ws;

  // workspace layout (floats)
  size_t np_off  = 0;                       // 4096
  size_t nh_off  = np_off + L;              // 4096
  size_t rs_off  = nh_off + L;              // 4096
  size_t cs_off  = rs_off + L;              // 4096
  size_t w2_off  = cs_off + L;              // 32768
  size_t amh_off = w2_off + (size_t)PP * D; // 2097152
  size_t amp_off = amh_off + (size_t)L * D; // 2097152
  size_t mp_off  = amp_off + (size_t)L * D; // 262144
  size_t mh_off  = mp_off + (size_t)L * PP; // 262144
  size_t pr_off  = mh_off + (size_t)L * PP; // 262144 (64 x 4096)
  size_t att_off = pr_off + (size_t)64 * L; // 16777216
  size_t gx_off  = att_off;                 // alias: gx (8388608) reuses dead att region
  size_t total   = att_off + (size_t)L * L;
  if (ws_size < total * sizeof(float)) return;  // workspace too small — bail safely

  float* np_  = ws + np_off;
  float* nh_  = ws + nh_off;
  float* rs   = ws + rs_off;
  float* cs   = ws + cs_off;
  float* w2t  = ws + w2_off;
  float* amh  = ws + amh_off;
  float* amp  = ws + amp_off;
  float* mtp  = ws + mp_off;
  float* mth  = ws + mh_off;
  float* pr   = ws + pr_off;
  float* att  = ws + att_off;
  float* gx   = ws + gx_off;

  norms_kernel<<<2 * L, 64, 0, stream>>>(fp, fh, np_, nh_);
  att_kernel<<<dim3(64, 64), 256, 0, stream>>>(fp, fh, np_, nh_, att);
  rowsum_kernel<<<L, 256, 0, stream>>>(att, rs);
  colpart_kernel<<<1024, 256, 0, stream>>>(att, pr);
  colsum_kernel<<<16, 256, 0, stream>>>(pr, cs);
  amh_kernel<<<dim3(8, 64), 256, 0, stream>>>(att, fh, rs, amh);
  amp_kernel<<<dim3(8, 64), 256, 0, stream>>>(att, fp, cs, amp);
  w2t_kernel<<<(PP * D + 255) / 256, 256, 0, stream>>>(mpw, w2t);
  match_kernel<<<2 * L, 64, 0, stream>>>(fp, fh, amh, amp, w2t, mtp, mth);
  gx_kernel<<<4 * (L / 8), 512, 0, stream>>>(mtp, mth, wih_f, wih_r, bih_f, bhh_f, bih_r, bhh_r, gx);
  lstm_kernel<<<4, 1024, 0, stream>>>(gx, whh_f, whh_r, out);
}

// Round 8
// 4994.431 us; speedup vs baseline: 1.0556x; 1.0475x over previous
//
#include <hip/hip_runtime.h>
#include <hip/hip_bf16.h>
#include <math.h>

#define L 4096
#define D 512
#define PP 64
#define HH 128
#define EPSF 1e-8f

// ---------------- norms: ||p_l||, ||h_l|| ----------------
__global__ __launch_bounds__(64) void norms_kernel(const float* __restrict__ fp, const float* __restrict__ fh,
                                                   float* __restrict__ np_, float* __restrict__ nh_) {
  int b = blockIdx.x;
  int which = b >> 12;
  int l = b & (L - 1);
  const float* v = (which ? fh : fp) + (size_t)l * D;
  float s = 0.f;
  for (int i = threadIdx.x; i < D; i += 64) { float x = v[i]; s += x * x; }
  for (int off = 32; off > 0; off >>= 1) s += __shfl_down(s, off);
  if (threadIdx.x == 0) (which ? nh_ : np_)[l] = sqrtf(s);
}

// ---------------- att = (p @ h^T) / clamp(np*nh) ----------------
__global__ __launch_bounds__(256) void att_kernel(const float* __restrict__ A, const float* __restrict__ B,
                                                  const float* __restrict__ np_, const float* __restrict__ nh_,
                                                  float* __restrict__ att) {
  __shared__ float As[64][33];
  __shared__ float Bs[64][33];
  const int t = threadIdx.x;
  const int tc = t & 15, tr = t >> 4;
  const int row0 = blockIdx.y * 64, col0 = blockIdx.x * 64;
  float acc[4][4] = {};
  for (int k0 = 0; k0 < D; k0 += 32) {
#pragma unroll
    for (int i = 0; i < 2; i++) {
      int idx = t + i * 256;            // float4 idx in [0,512)
      int r = idx >> 3, c4 = idx & 7;
      float4 va = *reinterpret_cast<const float4*>(&A[(size_t)(row0 + r) * D + k0 + c4 * 4]);
      float4 vb = *reinterpret_cast<const float4*>(&B[(size_t)(col0 + r) * D + k0 + c4 * 4]);
      As[r][c4 * 4 + 0] = va.x; As[r][c4 * 4 + 1] = va.y; As[r][c4 * 4 + 2] = va.z; As[r][c4 * 4 + 3] = va.w;
      Bs[r][c4 * 4 + 0] = vb.x; Bs[r][c4 * 4 + 1] = vb.y; Bs[r][c4 * 4 + 2] = vb.z; Bs[r][c4 * 4 + 3] = vb.w;
    }
    __syncthreads();
#pragma unroll
    for (int kk = 0; kk < 32; kk++) {
      float a[4], bb[4];
#pragma unroll
      for (int i = 0; i < 4; i++) a[i] = As[tr * 4 + i][kk];
#pragma unroll
      for (int j = 0; j < 4; j++) bb[j] = Bs[tc * 4 + j][kk];
#pragma unroll
      for (int i = 0; i < 4; i++)
#pragma unroll
        for (int j = 0; j < 4; j++) acc[i][j] += a[i] * bb[j];
    }
    __syncthreads();
  }
#pragma unroll
  for (int i = 0; i < 4; i++) {
    int l = row0 + tr * 4 + i;
    float npl = np_[l];
#pragma unroll
    for (int j = 0; j < 4; j++) {
      int cjj = col0 + tc * 4 + j;
      float den = npl * nh_[cjj];
      den = den > EPSF ? den : EPSF;
      att[(size_t)l * L + cjj] = acc[i][j] / den;
    }
  }
}

// ---------------- row sums of att ----------------
__global__ __launch_bounds__(256) void rowsum_kernel(const float* __restrict__ att, float* __restrict__ rs) {
  int row = blockIdx.x;
  float s = 0.f;
  for (int c = threadIdx.x; c < L; c += 256) s += att[(size_t)row * L + c];
  for (int off = 32; off > 0; off >>= 1) s += __shfl_down(s, off);
  __shared__ float ps[4];
  if ((threadIdx.x & 63) == 0) ps[threadIdx.x >> 6] = s;
  __syncthreads();
  if (threadIdx.x == 0) rs[row] = ps[0] + ps[1] + ps[2] + ps[3];
}

// ---------------- column sums of att (2-stage, deterministic) ----------------
__global__ __launch_bounds__(256) void colpart_kernel(const float* __restrict__ att, float* __restrict__ pr) {
  int bx = blockIdx.x & 15, by = blockIdx.x >> 4;
  int col = bx * 256 + threadIdx.x;
  int r0 = by * 64;
  float s = 0.f;
#pragma unroll 8
  for (int r = 0; r < 64; r++) s += att[(size_t)(r0 + r) * L + col];
  pr[(size_t)by * L + col] = s;
}
__global__ __launch_bounds__(256) void colsum_kernel(const float* __restrict__ pr, float* __restrict__ cs) {
  int col = blockIdx.x * 256 + threadIdx.x;
  float s = 0.f;
#pragma unroll 8
  for (int k = 0; k < 64; k++) s += pr[(size_t)k * L + col];
  cs[col] = s;
}

// ---------------- att_mean_h = (att @ h) / clamp(rs) ----------------
__global__ __launch_bounds__(256) void amh_kernel(const float* __restrict__ att, const float* __restrict__ B,
                                                  const float* __restrict__ rs, float* __restrict__ outm) {
  __shared__ float As[64][33];
  __shared__ float Bs[32][65];
  const int t = threadIdx.x;
  const int tc = t & 15, tr = t >> 4;
  const int row0 = blockIdx.y * 64, col0 = blockIdx.x * 64;
  float acc[4][4] = {};
  for (int k0 = 0; k0 < L; k0 += 32) {
#pragma unroll
    for (int i = 0; i < 2; i++) {
      int idx = t + i * 256;
      int r = idx >> 3, c4 = idx & 7;
      float4 va = *reinterpret_cast<const float4*>(&att[(size_t)(row0 + r) * L + k0 + c4 * 4]);
      As[r][c4 * 4 + 0] = va.x; As[r][c4 * 4 + 1] = va.y; As[r][c4 * 4 + 2] = va.z; As[r][c4 * 4 + 3] = va.w;
      int rb = idx >> 4, cb4 = idx & 15;
      float4 vb = *reinterpret_cast<const float4*>(&B[(size_t)(k0 + rb) * D + col0 + cb4 * 4]);
      Bs[rb][cb4 * 4 + 0] = vb.x; Bs[rb][cb4 * 4 + 1] = vb.y; Bs[rb][cb4 * 4 + 2] = vb.z; Bs[rb][cb4 * 4 + 3] = vb.w;
    }
    __syncthreads();
#pragma unroll
    for (int kk = 0; kk < 32; kk++) {
      float a[4], bb[4];
#pragma unroll
      for (int i = 0; i < 4; i++) a[i] = As[tr * 4 + i][kk];
#pragma unroll
      for (int j = 0; j < 4; j++) bb[j] = Bs[kk][tc * 4 + j];
#pragma unroll
      for (int i = 0; i < 4; i++)
#pragma unroll
        for (int j = 0; j < 4; j++) acc[i][j] += a[i] * bb[j];
    }
    __syncthreads();
  }
#pragma unroll
  for (int i = 0; i < 4; i++) {
    int l = row0 + tr * 4 + i;
    float den = rs[l];
    den = den > EPSF ? den : EPSF;
#pragma unroll
    for (int j = 0; j < 4; j++)
      outm[(size_t)l * D + col0 + tc * 4 + j] = acc[i][j] / den;
  }
}

// ---------------- att_mean_p = (att^T @ p) / clamp(cs) ----------------
__global__ __launch_bounds__(256) void amp_kernel(const float* __restrict__ att, const float* __restrict__ B,
                                                  const float* __restrict__ cs, float* __restrict__ outm) {
  __shared__ float As[64][33];
  __shared__ float Bs[32][65];
  const int t = threadIdx.x;
  const int tc = t & 15, tr = t >> 4;
  const int row0 = blockIdx.y * 64, col0 = blockIdx.x * 64;
  float acc[4][4] = {};
  for (int k0 = 0; k0 < L; k0 += 32) {
#pragma unroll
    for (int i = 0; i < 8; i++) {
      int idx = t + i * 256;          // 2048 scalars, coalesced in 64-wide groups
      int k = idx >> 6, jj = idx & 63;
      As[jj][k] = att[(size_t)(k0 + k) * L + row0 + jj];
    }
#pragma unroll
    for (int i = 0; i < 2; i++) {
      int idx = t + i * 256;
      int rb = idx >> 4, cb4 = idx & 15;
      float4 vb = *reinterpret_cast<const float4*>(&B[(size_t)(k0 + rb) * D + col0 + cb4 * 4]);
      Bs[rb][cb4 * 4 + 0] = vb.x; Bs[rb][cb4 * 4 + 1] = vb.y; Bs[rb][cb4 * 4 + 2] = vb.z; Bs[rb][cb4 * 4 + 3] = vb.w;
    }
    __syncthreads();
#pragma unroll
    for (int kk = 0; kk < 32; kk++) {
      float a[4], bb[4];
#pragma unroll
      for (int i = 0; i < 4; i++) a[i] = As[tr * 4 + i][kk];
#pragma unroll
      for (int j = 0; j < 4; j++) bb[j] = Bs[kk][tc * 4 + j];
#pragma unroll
      for (int i = 0; i < 4; i++)
#pragma unroll
        for (int j = 0; j < 4; j++) acc[i][j] += a[i] * bb[j];
    }
    __syncthreads();
  }
#pragma unroll
  for (int i = 0; i < 4; i++) {
    int jrow = row0 + tr * 4 + i;
    float den = cs[jrow];
    den = den > EPSF ? den : EPSF;
#pragma unroll
    for (int j = 0; j < 4; j++)
      outm[(size_t)jrow * D + col0 + tc * 4 + j] = acc[i][j] / den;
  }
}

// ---------------- w2 transposed: w2t[d][p] = mp_w[p][d]^2 ----------------
__global__ void w2t_kernel(const float* __restrict__ mpw, float* __restrict__ w2t) {
  int o = blockIdx.x * blockDim.x + threadIdx.x;
  if (o >= PP * D) return;
  int dd = o >> 6, p = o & 63;
  float v = mpw[(size_t)p * D + dd];
  w2t[o] = v * v;
}

// ---------------- multi-perspective weighted cosine ----------------
__global__ __launch_bounds__(64) void match_kernel(const float* __restrict__ fp, const float* __restrict__ fh,
                                                   const float* __restrict__ amh, const float* __restrict__ amp,
                                                   const float* __restrict__ w2t,
                                                   float* __restrict__ match_p, float* __restrict__ match_h) {
  int b = blockIdx.x;
  int which = b >> 12;
  int l = b & (L - 1);
  const float* v1 = (which ? fh : fp) + (size_t)l * D;
  const float* v2 = (which ? amp : amh) + (size_t)l * D;
  __shared__ float s1[D], s2[D];
  int t = threadIdx.x;
#pragma unroll
  for (int i = 0; i < 2; i++) {
    int f4 = t + 64 * i;
    *reinterpret_cast<float4*>(&s1[f4 * 4]) = *reinterpret_cast<const float4*>(&v1[f4 * 4]);
    *reinterpret_cast<float4*>(&s2[f4 * 4]) = *reinterpret_cast<const float4*>(&v2[f4 * 4]);
  }
  __syncthreads();
  float num = 0.f, a1 = 0.f, a2 = 0.f;
  for (int dd = 0; dd < D; dd++) {
    float wv = w2t[dd * PP + t];
    float x = s1[dd], y = s2[dd];
    num += wv * x * y;
    a1 += wv * x * x;
    a2 += wv * y * y;
  }
  float n1 = fmaxf(sqrtf(a1), EPSF), n2 = fmaxf(sqrtf(a2), EPSF);
  float* outm = which ? match_h : match_p;
  outm[(size_t)l * PP + t] = num / (n1 * n2);
}

// ---------------- gx = match @ w_ih^T + (b_ih + b_hh), time-reversed for odd dirs ----------------
__global__ __launch_bounds__(512) void gx_kernel(const float* __restrict__ match_p, const float* __restrict__ match_h,
                                                 const float* __restrict__ wih_f, const float* __restrict__ wih_r,
                                                 const float* __restrict__ bih_f, const float* __restrict__ bhh_f,
                                                 const float* __restrict__ bih_r, const float* __restrict__ bhh_r,
                                                 float* __restrict__ gx) {
  int b = blockIdx.x;
  int dir = b >> 9;
  int chunk = b & 511;
  const float* m_src = (dir < 2) ? match_p : match_h;
  const float* wih = (dir & 1) ? wih_r : wih_f;
  const float* bi = (dir & 1) ? bih_r : bih_f;
  const float* bh = (dir & 1) ? bhh_r : bhh_f;
  __shared__ float m[8][PP];
  int t = threadIdx.x;
  {
    int tt = t >> 6, p = t & 63;
    int tstep = chunk * 8 + tt;
    int row = (dir & 1) ? (L - 1 - tstep) : tstep;
    m[tt][p] = m_src[(size_t)row * PP + p];
  }
  __syncthreads();
  int j = t;
  float bias = bi[j] + bh[j];
  float acc[8];
#pragma unroll
  for (int tt = 0; tt < 8; tt++) acc[tt] = bias;
  for (int p = 0; p < PP; p++) {
    float wv = wih[(size_t)j * PP + p];
#pragma unroll
    for (int tt = 0; tt < 8; tt++) acc[tt] += wv * m[tt][p];
  }
#pragma unroll
  for (int tt = 0; tt < 8; tt++)
    gx[((size_t)dir * L + chunk * 8 + tt) * 512 + j] = acc[tt];
}

// opaque 16B load: the load ITSELF is inline asm, so LLVM cannot
// rematerialize it (it is not a load in its model — it is an opaque def).
// vmcnt(0) is embedded in the same asm block so the output registers are
// data-complete at the def point (no waitcnt-hoisting hazard, rule #18).
__device__ __forceinline__ float4 load4_opaque(const float* p) {
  float4 v;
  asm volatile("global_load_dwordx4 %0, %1, off\n\ts_waitcnt vmcnt(0)"
               : "=v"(v) : "v"(p));
  return v;
}

// ---------------- 4 sequential LSTMs (persistent blocks) ----------------
// ROUNDS 1-7 LESSON (unified): the RA remats read-only global weight loads
// into the 4096-step loop no matter what pins/hints/occupancy settings are
// applied (VGPR stuck at 52-84 across 512/1024-thread, fp16/fp32 variants;
// per-step pinned at ~2300 cyc = re-issue of 16 dwordx4 + 64-bit addressing
// ~190 VALU ops/thread, L2 latency hidden by 16 waves). An asm "+v" pin
// never helps because LLVM recreates the VALUE by re-loading; the load was
// never opaque. THIS round the load itself is inline asm (load4_opaque) —
// rematerialization is impossible by construction. Demand ~95 VGPR fits the
// 128/wave budget at 16 waves (4/EU). Structure: 16-lane group owns 8
// outputs; lane g holds k-seg [8g,8g+8) fp32 = 64 VGPR. Matvec floor:
// 64 fma x 16 waves / 4 SIMD x 2 cyc = 512 cyc/step.
// h: single fp32 h_sh[128]; lane reads 2 float4 (4-way bank alias on each,
// ~1.6x on 2 of ~90 instrs — negligible); scalar writes by tid<128.
__global__ __attribute__((amdgpu_waves_per_eu(4, 4))) __launch_bounds__(1024)
void lstm_kernel(const float* __restrict__ gx,
                 const float* __restrict__ whh_f, const float* __restrict__ whh_r,
                 float* __restrict__ out) {
  const int dir = blockIdx.x;
  const float* __restrict__ whh = (dir & 1) ? whh_r : whh_f;
  const int tid = threadIdx.x;
  const int g = tid & 15;                 // k-segment index within group
  const int jbase = (tid >> 4) << 3;      // first of this group's 8 outputs
  const int jmine = jbase | (tid & 7);    // the output this thread finalizes

  float4 w4[8][2];
#pragma unroll
  for (int jj = 0; jj < 8; jj++) {
    w4[jj][0] = load4_opaque(&whh[(size_t)(jbase + jj) * HH + g * 8]);
    w4[jj][1] = load4_opaque(&whh[(size_t)(jbase + jj) * HH + g * 8 + 4]);
  }

  __shared__ __align__(16) float h_sh[HH];
  __shared__ float act[512];
  if (tid < HH) h_sh[tid] = 0.f;
  __syncthreads();

  const float* __restrict__ gsrc = gx + (size_t)dir * L * 512;
  float gval = gsrc[jmine];
  const int m = tid & 127;
  const int is_g_gate = ((jmine >> 7) == 2);    // wave-uniform
  const int b0 = tid & 1, b1 = tid & 2, b2 = tid & 4;
  float c = 0.f, h = 0.f;

  for (int t = 0; t < L; t++) {
    float gnext = (t + 1 < L) ? gsrc[(size_t)(t + 1) * 512 + jmine] : 0.f;
    float4 hf0 = *reinterpret_cast<const float4*>(&h_sh[g * 8]);
    float4 hf1 = *reinterpret_cast<const float4*>(&h_sh[g * 8 + 4]);
    // 8 outputs x 8 k, all fp32, all operands in VGPRs
    float acc[8];
#pragma unroll
    for (int jj = 0; jj < 8; jj++) {
      float s0 = w4[jj][0].x * hf0.x;
      float s1 = w4[jj][0].y * hf0.y;
      s0 = fmaf(w4[jj][0].z, hf0.z, s0);
      s1 = fmaf(w4[jj][0].w, hf0.w, s1);
      s0 = fmaf(w4[jj][1].x, hf1.x, s0);
      s1 = fmaf(w4[jj][1].y, hf1.y, s1);
      s0 = fmaf(w4[jj][1].z, hf1.z, s0);
      s1 = fmaf(w4[jj][1].w, hf1.w, s1);
      acc[jj] = s0 + s1;
    }
    // compacting butterfly over the 8-lane window, then combine k-halves
    float r4[4];
#pragma unroll
    for (int i = 0; i < 4; i++) {
      float keep = b0 ? acc[2 * i + 1] : acc[2 * i];
      float send = b0 ? acc[2 * i] : acc[2 * i + 1];
      r4[i] = keep + __shfl_xor(send, 1);
    }
    float r2[2];
#pragma unroll
    for (int u = 0; u < 2; u++) {
      float keep = b1 ? r4[2 * u + 1] : r4[2 * u];
      float send = b1 ? r4[2 * u] : r4[2 * u + 1];
      r2[u] = keep + __shfl_xor(send, 2);
    }
    float keep1 = b2 ? r2[1] : r2[0];
    float send1 = b2 ? r2[0] : r2[1];
    float r1 = keep1 + __shfl_xor(send1, 4);
    float z = r1 + __shfl_xor(r1, 8) + gval;
    float a;
    if (is_g_gate) {
      float e = __expf(2.f * z);
      a = 1.f - 2.f / (e + 1.f);
    } else {
      a = 1.f / (1.f + __expf(-z));
    }
    act[jmine] = a;                       // dup pair writes same value
    __syncthreads();
    // c/h computed redundantly by all 1024 threads; tid<128 stores
    float iv = act[m], fv = act[HH + m], gg = act[2 * HH + m], ov = act[3 * HH + m];
    c = fv * c + iv * gg;
    float e2 = __expf(2.f * c);
    h = ov * (1.f - 2.f / (e2 + 1.f));
    if (tid < HH) h_sh[m] = h;
    __syncthreads();
    gval = gnext;
  }
  if (tid < HH) out[dir * HH + tid] = h;
}

extern "C" void kernel_launch(void* const* d_in, const int* in_sizes, int n_in,
                              void* d_out, int out_size, void* d_ws, size_t ws_size,
                              hipStream_t stream) {
  const float* fp    = (const float*)d_in[0];
  const float* fh    = (const float*)d_in[1];
  const float* mpw   = (const float*)d_in[2];
  const float* wih_f = (const float*)d_in[3];
  const float* whh_f = (const float*)d_in[4];
  const float* bih_f = (const float*)d_in[5];
  const float* bhh_f = (const float*)d_in[6];
  const float* wih_r = (const float*)d_in[7];
  const float* whh_r = (const float*)d_in[8];
  const float* bih_r = (const float*)d_in[9];
  const float* bhh_r = (const float*)d_in[10];
  float* out = (float*)d_out;
  float* ws = (float*)d_ws;

  // workspace layout (floats)
  size_t np_off  = 0;                       // 4096
  size_t nh_off  = np_off + L;              // 4096
  size_t rs_off  = nh_off + L;              // 4096
  size_t cs_off  = rs_off + L;              // 4096
  size_t w2_off  = cs_off + L;              // 32768
  size_t amh_off = w2_off + (size_t)PP * D; // 2097152
  size_t amp_off = amh_off + (size_t)L * D; // 2097152
  size_t mp_off  = amp_off + (size_t)L * D; // 262144
  size_t mh_off  = mp_off + (size_t)L * PP; // 262144
  size_t pr_off  = mh_off + (size_t)L * PP; // 262144 (64 x 4096)
  size_t att_off = pr_off + (size_t)64 * L; // 16777216
  size_t gx_off  = att_off;                 // alias: gx (8388608) reuses dead att region
  size_t total   = att_off + (size_t)L * L;
  if (ws_size < total * sizeof(float)) return;  // workspace too small — bail safely

  float* np_  = ws + np_off;
  float* nh_  = ws + nh_off;
  float* rs   = ws + rs_off;
  float* cs   = ws + cs_off;
  float* w2t  = ws + w2_off;
  float* amh  = ws + amh_off;
  float* amp  = ws + amp_off;
  float* mtp  = ws + mp_off;
  float* mth  = ws + mh_off;
  float* pr   = ws + pr_off;
  float* att  = ws + att_off;
  float* gx   = ws + gx_off;

  norms_kernel<<<2 * L, 64, 0, stream>>>(fp, fh, np_, nh_);
  att_kernel<<<dim3(64, 64), 256, 0, stream>>>(fp, fh, np_, nh_, att);
  rowsum_kernel<<<L, 256, 0, stream>>>(att, rs);
  colpart_kernel<<<1024, 256, 0, stream>>>(att, pr);
  colsum_kernel<<<16, 256, 0, stream>>>(pr, cs);
  amh_kernel<<<dim3(8, 64), 256, 0, stream>>>(att, fh, rs, amh);
  amp_kernel<<<dim3(8, 64), 256, 0, stream>>>(att, fp, cs, amp);
  w2t_kernel<<<(PP * D + 255) / 256, 256, 0, stream>>>(mpw, w2t);
  match_kernel<<<2 * L, 64, 0, stream>>>(fp, fh, amh, amp, w2t, mtp, mth);
  gx_kernel<<<4 * (L / 8), 512, 0, stream>>>(mtp, mth, wih_f, wih_r, bih_f, bhh_f, bih_r, bhh_r, gx);
  lstm_kernel<<<4, 1024, 0, stream>>>(gx, whh_f, whh_r, out);
}

// Round 9
// 4458.049 us; speedup vs baseline: 1.1826x; 1.1203x over previous
//
#include <hip/hip_runtime.h>
#include <hip/hip_bf16.h>
#include <math.h>

#define L 4096
#define D 512
#define PP 64
#define HH 128
#define EPSF 1e-8f

// ---------------- norms: ||p_l||, ||h_l|| ----------------
__global__ __launch_bounds__(64) void norms_kernel(const float* __restrict__ fp, const float* __restrict__ fh,
                                                   float* __restrict__ np_, float* __restrict__ nh_) {
  int b = blockIdx.x;
  int which = b >> 12;
  int l = b & (L - 1);
  const float* v = (which ? fh : fp) + (size_t)l * D;
  float s = 0.f;
  for (int i = threadIdx.x; i < D; i += 64) { float x = v[i]; s += x * x; }
  for (int off = 32; off > 0; off >>= 1) s += __shfl_down(s, off);
  if (threadIdx.x == 0) (which ? nh_ : np_)[l] = sqrtf(s);
}

// ---------------- att = (p @ h^T) / clamp(np*nh) ----------------
__global__ __launch_bounds__(256) void att_kernel(const float* __restrict__ A, const float* __restrict__ B,
                                                  const float* __restrict__ np_, const float* __restrict__ nh_,
                                                  float* __restrict__ att) {
  __shared__ float As[64][33];
  __shared__ float Bs[64][33];
  const int t = threadIdx.x;
  const int tc = t & 15, tr = t >> 4;
  const int row0 = blockIdx.y * 64, col0 = blockIdx.x * 64;
  float acc[4][4] = {};
  for (int k0 = 0; k0 < D; k0 += 32) {
#pragma unroll
    for (int i = 0; i < 2; i++) {
      int idx = t + i * 256;            // float4 idx in [0,512)
      int r = idx >> 3, c4 = idx & 7;
      float4 va = *reinterpret_cast<const float4*>(&A[(size_t)(row0 + r) * D + k0 + c4 * 4]);
      float4 vb = *reinterpret_cast<const float4*>(&B[(size_t)(col0 + r) * D + k0 + c4 * 4]);
      As[r][c4 * 4 + 0] = va.x; As[r][c4 * 4 + 1] = va.y; As[r][c4 * 4 + 2] = va.z; As[r][c4 * 4 + 3] = va.w;
      Bs[r][c4 * 4 + 0] = vb.x; Bs[r][c4 * 4 + 1] = vb.y; Bs[r][c4 * 4 + 2] = vb.z; Bs[r][c4 * 4 + 3] = vb.w;
    }
    __syncthreads();
#pragma unroll
    for (int kk = 0; kk < 32; kk++) {
      float a[4], bb[4];
#pragma unroll
      for (int i = 0; i < 4; i++) a[i] = As[tr * 4 + i][kk];
#pragma unroll
      for (int j = 0; j < 4; j++) bb[j] = Bs[tc * 4 + j][kk];
#pragma unroll
      for (int i = 0; i < 4; i++)
#pragma unroll
        for (int j = 0; j < 4; j++) acc[i][j] += a[i] * bb[j];
    }
    __syncthreads();
  }
#pragma unroll
  for (int i = 0; i < 4; i++) {
    int l = row0 + tr * 4 + i;
    float npl = np_[l];
#pragma unroll
    for (int j = 0; j < 4; j++) {
      int cjj = col0 + tc * 4 + j;
      float den = npl * nh_[cjj];
      den = den > EPSF ? den : EPSF;
      att[(size_t)l * L + cjj] = acc[i][j] / den;
    }
  }
}

// ---------------- row sums of att ----------------
__global__ __launch_bounds__(256) void rowsum_kernel(const float* __restrict__ att, float* __restrict__ rs) {
  int row = blockIdx.x;
  float s = 0.f;
  for (int c = threadIdx.x; c < L; c += 256) s += att[(size_t)row * L + c];
  for (int off = 32; off > 0; off >>= 1) s += __shfl_down(s, off);
  __shared__ float ps[4];
  if ((threadIdx.x & 63) == 0) ps[threadIdx.x >> 6] = s;
  __syncthreads();
  if (threadIdx.x == 0) rs[row] = ps[0] + ps[1] + ps[2] + ps[3];
}

// ---------------- column sums of att (2-stage, deterministic) ----------------
__global__ __launch_bounds__(256) void colpart_kernel(const float* __restrict__ att, float* __restrict__ pr) {
  int bx = blockIdx.x & 15, by = blockIdx.x >> 4;
  int col = bx * 256 + threadIdx.x;
  int r0 = by * 64;
  float s = 0.f;
#pragma unroll 8
  for (int r = 0; r < 64; r++) s += att[(size_t)(r0 + r) * L + col];
  pr[(size_t)by * L + col] = s;
}
__global__ __launch_bounds__(256) void colsum_kernel(const float* __restrict__ pr, float* __restrict__ cs) {
  int col = blockIdx.x * 256 + threadIdx.x;
  float s = 0.f;
#pragma unroll 8
  for (int k = 0; k < 64; k++) s += pr[(size_t)k * L + col];
  cs[col] = s;
}

// ---------------- att_mean_h = (att @ h) / clamp(rs) ----------------
__global__ __launch_bounds__(256) void amh_kernel(const float* __restrict__ att, const float* __restrict__ B,
                                                  const float* __restrict__ rs, float* __restrict__ outm) {
  __shared__ float As[64][33];
  __shared__ float Bs[32][65];
  const int t = threadIdx.x;
  const int tc = t & 15, tr = t >> 4;
  const int row0 = blockIdx.y * 64, col0 = blockIdx.x * 64;
  float acc[4][4] = {};
  for (int k0 = 0; k0 < L; k0 += 32) {
#pragma unroll
    for (int i = 0; i < 2; i++) {
      int idx = t + i * 256;
      int r = idx >> 3, c4 = idx & 7;
      float4 va = *reinterpret_cast<const float4*>(&att[(size_t)(row0 + r) * L + k0 + c4 * 4]);
      As[r][c4 * 4 + 0] = va.x; As[r][c4 * 4 + 1] = va.y; As[r][c4 * 4 + 2] = va.z; As[r][c4 * 4 + 3] = va.w;
      int rb = idx >> 4, cb4 = idx & 15;
      float4 vb = *reinterpret_cast<const float4*>(&B[(size_t)(k0 + rb) * D + col0 + cb4 * 4]);
      Bs[rb][cb4 * 4 + 0] = vb.x; Bs[rb][cb4 * 4 + 1] = vb.y; Bs[rb][cb4 * 4 + 2] = vb.z; Bs[rb][cb4 * 4 + 3] = vb.w;
    }
    __syncthreads();
#pragma unroll
    for (int kk = 0; kk < 32; kk++) {
      float a[4], bb[4];
#pragma unroll
      for (int i = 0; i < 4; i++) a[i] = As[tr * 4 + i][kk];
#pragma unroll
      for (int j = 0; j < 4; j++) bb[j] = Bs[kk][tc * 4 + j];
#pragma unroll
      for (int i = 0; i < 4; i++)
#pragma unroll
        for (int j = 0; j < 4; j++) acc[i][j] += a[i] * bb[j];
    }
    __syncthreads();
  }
#pragma unroll
  for (int i = 0; i < 4; i++) {
    int l = row0 + tr * 4 + i;
    float den = rs[l];
    den = den > EPSF ? den : EPSF;
#pragma unroll
    for (int j = 0; j < 4; j++)
      outm[(size_t)l * D + col0 + tc * 4 + j] = acc[i][j] / den;
  }
}

// ---------------- att_mean_p = (att^T @ p) / clamp(cs) ----------------
__global__ __launch_bounds__(256) void amp_kernel(const float* __restrict__ att, const float* __restrict__ B,
                                                  const float* __restrict__ cs, float* __restrict__ outm) {
  __shared__ float As[64][33];
  __shared__ float Bs[32][65];
  const int t = threadIdx.x;
  const int tc = t & 15, tr = t >> 4;
  const int row0 = blockIdx.y * 64, col0 = blockIdx.x * 64;
  float acc[4][4] = {};
  for (int k0 = 0; k0 < L; k0 += 32) {
#pragma unroll
    for (int i = 0; i < 8; i++) {
      int idx = t + i * 256;          // 2048 scalars, coalesced in 64-wide groups
      int k = idx >> 6, jj = idx & 63;
      As[jj][k] = att[(size_t)(k0 + k) * L + row0 + jj];
    }
#pragma unroll
    for (int i = 0; i < 2; i++) {
      int idx = t + i * 256;
      int rb = idx >> 4, cb4 = idx & 15;
      float4 vb = *reinterpret_cast<const float4*>(&B[(size_t)(k0 + rb) * D + col0 + cb4 * 4]);
      Bs[rb][cb4 * 4 + 0] = vb.x; Bs[rb][cb4 * 4 + 1] = vb.y; Bs[rb][cb4 * 4 + 2] = vb.z; Bs[rb][cb4 * 4 + 3] = vb.w;
    }
    __syncthreads();
#pragma unroll
    for (int kk = 0; kk < 32; kk++) {
      float a[4], bb[4];
#pragma unroll
      for (int i = 0; i < 4; i++) a[i] = As[tr * 4 + i][kk];
#pragma unroll
      for (int j = 0; j < 4; j++) bb[j] = Bs[kk][tc * 4 + j];
#pragma unroll
      for (int i = 0; i < 4; i++)
#pragma unroll
        for (int j = 0; j < 4; j++) acc[i][j] += a[i] * bb[j];
    }
    __syncthreads();
  }
#pragma unroll
  for (int i = 0; i < 4; i++) {
    int jrow = row0 + tr * 4 + i;
    float den = cs[jrow];
    den = den > EPSF ? den : EPSF;
#pragma unroll
    for (int j = 0; j < 4; j++)
      outm[(size_t)jrow * D + col0 + tc * 4 + j] = acc[i][j] / den;
  }
}

// ---------------- w2 transposed: w2t[d][p] = mp_w[p][d]^2 ----------------
__global__ void w2t_kernel(const float* __restrict__ mpw, float* __restrict__ w2t) {
  int o = blockIdx.x * blockDim.x + threadIdx.x;
  if (o >= PP * D) return;
  int dd = o >> 6, p = o & 63;
  float v = mpw[(size_t)p * D + dd];
  w2t[o] = v * v;
}

// ---------------- multi-perspective weighted cosine ----------------
__global__ __launch_bounds__(64) void match_kernel(const float* __restrict__ fp, const float* __restrict__ fh,
                                                   const float* __restrict__ amh, const float* __restrict__ amp,
                                                   const float* __restrict__ w2t,
                                                   float* __restrict__ match_p, float* __restrict__ match_h) {
  int b = blockIdx.x;
  int which = b >> 12;
  int l = b & (L - 1);
  const float* v1 = (which ? fh : fp) + (size_t)l * D;
  const float* v2 = (which ? amp : amh) + (size_t)l * D;
  __shared__ float s1[D], s2[D];
  int t = threadIdx.x;
#pragma unroll
  for (int i = 0; i < 2; i++) {
    int f4 = t + 64 * i;
    *reinterpret_cast<float4*>(&s1[f4 * 4]) = *reinterpret_cast<const float4*>(&v1[f4 * 4]);
    *reinterpret_cast<float4*>(&s2[f4 * 4]) = *reinterpret_cast<const float4*>(&v2[f4 * 4]);
  }
  __syncthreads();
  float num = 0.f, a1 = 0.f, a2 = 0.f;
  for (int dd = 0; dd < D; dd++) {
    float wv = w2t[dd * PP + t];
    float x = s1[dd], y = s2[dd];
    num += wv * x * y;
    a1 += wv * x * x;
    a2 += wv * y * y;
  }
  float n1 = fmaxf(sqrtf(a1), EPSF), n2 = fmaxf(sqrtf(a2), EPSF);
  float* outm = which ? match_h : match_p;
  outm[(size_t)l * PP + t] = num / (n1 * n2);
}

// ---------------- gx = match @ w_ih^T + (b_ih + b_hh), time-reversed for odd dirs ----------------
__global__ __launch_bounds__(512) void gx_kernel(const float* __restrict__ match_p, const float* __restrict__ match_h,
                                                 const float* __restrict__ wih_f, const float* __restrict__ wih_r,
                                                 const float* __restrict__ bih_f, const float* __restrict__ bhh_f,
                                                 const float* __restrict__ bih_r, const float* __restrict__ bhh_r,
                                                 float* __restrict__ gx) {
  int b = blockIdx.x;
  int dir = b >> 9;
  int chunk = b & 511;
  const float* m_src = (dir < 2) ? match_p : match_h;
  const float* wih = (dir & 1) ? wih_r : wih_f;
  const float* bi = (dir & 1) ? bih_r : bih_f;
  const float* bh = (dir & 1) ? bhh_r : bhh_f;
  __shared__ float m[8][PP];
  int t = threadIdx.x;
  {
    int tt = t >> 6, p = t & 63;
    int tstep = chunk * 8 + tt;
    int row = (dir & 1) ? (L - 1 - tstep) : tstep;
    m[tt][p] = m_src[(size_t)row * PP + p];
  }
  __syncthreads();
  int j = t;
  float bias = bi[j] + bh[j];
  float acc[8];
#pragma unroll
  for (int tt = 0; tt < 8; tt++) acc[tt] = bias;
  for (int p = 0; p < PP; p++) {
    float wv = wih[(size_t)j * PP + p];
#pragma unroll
    for (int tt = 0; tt < 8; tt++) acc[tt] += wv * m[tt][p];
  }
#pragma unroll
  for (int tt = 0; tt < 8; tt++)
    gx[((size_t)dir * L + chunk * 8 + tt) * 512 + j] = acc[tt];
}

// opaque 16B load (r8): inline-asm def, cannot be rematerialized; vmcnt(0)
// embedded so the outputs are data-complete at the def (rule #18 safe).
__device__ __forceinline__ float4 load4_opaque(const float* p) {
  float4 v;
  asm volatile("global_load_dwordx4 %0, %1, off\n\ts_waitcnt vmcnt(0)"
               : "=v"(v) : "v"(p));
  return v;
}

// cross-lane XOR exchange on the VALU (DPP), not the DS pipe.
// 0xB1 = quad_perm [1,0,3,2] (xor1); 0x4E = quad_perm [2,3,0,1] (xor2);
// 0x128 = row_ror:8 == xor8 within each 16-lane row.
template <int CTRL>
__device__ __forceinline__ float xdpp(float x) {
  return __int_as_float(__builtin_amdgcn_mov_dpp(__float_as_int(x), CTRL, 0xf, 0xf, true));
}

// ---------------- 4 sequential LSTMs (persistent blocks) ----------------
// ROUND-8 DIAGNOSIS: per-step time (~2150 cyc) was DS-PIPE bound, not weight
// bound: 7 __shfl_xor/thread (112 ds ops/step), 32 ds_read_b128 (4-way bank
// aliased), 16-wave redundant act reads -> ~1600 cyc/step on the single LDS
// unit. Four different weight-residency schemes (r5-r8) moved nothing because
// weights were never the critical path.
// ROUND-9 FIX: (1) butterfly exchange via DPP (VALU) — group output bits
// remapped to {γ0,γ1,γ3} so masks are xor1/xor2/xor8 (all DPP-able); only the
// k-half combine (xor4, γ2) stays as one ds_swizzle -> DS shuffle ops 7->1.
// (2) phase 2 (c/h) restricted to tid<128 (2 waves) — kills 14 waves of
// redundant act reads + expf. (3) h stored at stride-12 floats per k-octet
// (16B aligned, banks 2-way max) -> kills the counted 4-way hf conflict.
// Lane (sec,γ) of wave w: outputs jsec..jsec+8 (jsec = w*32+sec*8), k-octet
// [8γ,8γ+8). After butterfly lane holds output o=γ0+2γ1+4γ3 summed over its
// γ2-half; shfl_xor(4) completes K. γ2-twins duplicate (benign same-addr
// same-value act store).
__global__ __attribute__((amdgpu_waves_per_eu(4, 4))) __launch_bounds__(1024)
void lstm_kernel(const float* __restrict__ gx,
                 const float* __restrict__ whh_f, const float* __restrict__ whh_r,
                 float* __restrict__ out) {
  const int dir = blockIdx.x;
  const float* __restrict__ whh = (dir & 1) ? whh_r : whh_f;
  const int tid = threadIdx.x;
  const int lane = tid & 63;
  const int wv = tid >> 6;            // wave 0..15
  const int sec = lane >> 4;          // 16-lane section 0..3
  const int gam = lane & 15;          // γ
  const int o_of = (gam & 1) | (((gam >> 1) & 1) << 1) | (((gam >> 3) & 1) << 2);
  const int jsec = wv * 32 + sec * 8;
  const int jmine = jsec + o_of;      // output this lane finalizes
  const int kbase = gam * 8;          // k-octet

  float4 w4[8][2];
#pragma unroll
  for (int jj = 0; jj < 8; jj++) {
    w4[jj][0] = load4_opaque(&whh[(size_t)(jsec + jj) * HH + kbase]);
    w4[jj][1] = load4_opaque(&whh[(size_t)(jsec + jj) * HH + kbase + 4]);
  }

  __shared__ __align__(16) float h_pad[16 * 12];  // octet κ at float offset 12κ
  __shared__ float act[512];
  if (tid < 192) h_pad[tid] = 0.f;
  __syncthreads();

  const float* __restrict__ gsrc = gx + (size_t)dir * L * 512;
  float gval = gsrc[jmine];
  const int m = tid & 127;
  const int is_g_gate = ((jmine >> 7) == 2);    // wave-uniform
  const int s0b = gam & 1, s1b = gam & 2, s3b = gam & 8;
  const int hoff = gam * 12;
  const int hwr = (m >> 3) * 12 + (m & 7);      // phase-2 write slot
  float c = 0.f, h = 0.f;

  for (int t = 0; t < L; t++) {
    float gnext = (t + 1 < L) ? gsrc[(size_t)(t + 1) * 512 + jmine] : 0.f;
    float4 hf0 = *reinterpret_cast<const float4*>(&h_pad[hoff]);
    float4 hf1 = *reinterpret_cast<const float4*>(&h_pad[hoff + 4]);
    float acc[8];
#pragma unroll
    for (int jj = 0; jj < 8; jj++) {
      float s0 = w4[jj][0].x * hf0.x;
      float s1 = w4[jj][0].y * hf0.y;
      s0 = fmaf(w4[jj][0].z, hf0.z, s0);
      s1 = fmaf(w4[jj][0].w, hf0.w, s1);
      s0 = fmaf(w4[jj][1].x, hf1.x, s0);
      s1 = fmaf(w4[jj][1].y, hf1.y, s1);
      s0 = fmaf(w4[jj][1].z, hf1.z, s0);
      s1 = fmaf(w4[jj][1].w, hf1.w, s1);
      acc[jj] = s0 + s1;
    }
    // compacting butterfly: xor1, xor2 (quad_perm), xor8 (row_ror:8) — VALU
    float r4[4];
#pragma unroll
    for (int i = 0; i < 4; i++) {
      float keep = s0b ? acc[2 * i + 1] : acc[2 * i];
      float send = s0b ? acc[2 * i] : acc[2 * i + 1];
      r4[i] = keep + xdpp<0xB1>(send);
    }
    float r2[2];
#pragma unroll
    for (int u = 0; u < 2; u++) {
      float keep = s1b ? r4[2 * u + 1] : r4[2 * u];
      float send = s1b ? r4[2 * u] : r4[2 * u + 1];
      r2[u] = keep + xdpp<0x4E>(send);
    }
    float keep1 = s3b ? r2[1] : r2[0];
    float send1 = s3b ? r2[0] : r2[1];
    float r1 = keep1 + xdpp<0x128>(send1);
    // k-half combine (γ2): the single remaining DS shuffle
    float z = r1 + __shfl_xor(r1, 4) + gval;
    float a;
    if (is_g_gate) {
      float e = __expf(2.f * z);
      a = 1.f - 2.f / (e + 1.f);
    } else {
      a = 1.f / (1.f + __expf(-z));
    }
    act[jmine] = a;                       // γ2-twins write same value
    __syncthreads();
    if (tid < HH) {                       // 2 waves only
      float iv = act[m], fv = act[HH + m], gg = act[2 * HH + m], ov = act[3 * HH + m];
      c = fv * c + iv * gg;
      float e2 = __expf(2.f * c);
      h = ov * (1.f - 2.f / (e2 + 1.f));
      h_pad[hwr] = h;
    }
    __syncthreads();
    gval = gnext;
  }
  if (tid < HH) out[dir * HH + tid] = h;
}

extern "C" void kernel_launch(void* const* d_in, const int* in_sizes, int n_in,
                              void* d_out, int out_size, void* d_ws, size_t ws_size,
                              hipStream_t stream) {
  const float* fp    = (const float*)d_in[0];
  const float* fh    = (const float*)d_in[1];
  const float* mpw   = (const float*)d_in[2];
  const float* wih_f = (const float*)d_in[3];
  const float* whh_f = (const float*)d_in[4];
  const float* bih_f = (const float*)d_in[5];
  const float* bhh_f = (const float*)d_in[6];
  const float* wih_r = (const float*)d_in[7];
  const float* whh_r = (const float*)d_in[8];
  const float* bih_r = (const float*)d_in[9];
  const float* bhh_r = (const float*)d_in[10];
  float* out = (float*)d_out;
  float* ws = (float*)d_ws;

  // workspace layout (floats)
  size_t np_off  = 0;                       // 4096
  size_t nh_off  = np_off + L;              // 4096
  size_t rs_off  = nh_off + L;              // 4096
  size_t cs_off  = rs_off + L;              // 4096
  size_t w2_off  = cs_off + L;              // 32768
  size_t amh_off = w2_off + (size_t)PP * D; // 2097152
  size_t amp_off = amh_off + (size_t)L * D; // 2097152
  size_t mp_off  = amp_off + (size_t)L * D; // 262144
  size_t mh_off  = mp_off + (size_t)L * PP; // 262144
  size_t pr_off  = mh_off + (size_t)L * PP; // 262144 (64 x 4096)
  size_t att_off = pr_off + (size_t)64 * L; // 16777216
  size_t gx_off  = att_off;                 // alias: gx (8388608) reuses dead att region
  size_t total   = att_off + (size_t)L * L;
  if (ws_size < total * sizeof(float)) return;  // workspace too small — bail safely

  float* np_  = ws + np_off;
  float* nh_  = ws + nh_off;
  float* rs   = ws + rs_off;
  float* cs   = ws + cs_off;
  float* w2t  = ws + w2_off;
  float* amh  = ws + amh_off;
  float* amp  = ws + amp_off;
  float* mtp  = ws + mp_off;
  float* mth  = ws + mh_off;
  float* pr   = ws + pr_off;
  float* att  = ws + att_off;
  float* gx   = ws + gx_off;

  norms_kernel<<<2 * L, 64, 0, stream>>>(fp, fh, np_, nh_);
  att_kernel<<<dim3(64, 64), 256, 0, stream>>>(fp, fh, np_, nh_, att);
  rowsum_kernel<<<L, 256, 0, stream>>>(att, rs);
  colpart_kernel<<<1024, 256, 0, stream>>>(att, pr);
  colsum_kernel<<<16, 256, 0, stream>>>(pr, cs);
  amh_kernel<<<dim3(8, 64), 256, 0, stream>>>(att, fh, rs, amh);
  amp_kernel<<<dim3(8, 64), 256, 0, stream>>>(att, fp, cs, amp);
  w2t_kernel<<<(PP * D + 255) / 256, 256, 0, stream>>>(mpw, w2t);
  match_kernel<<<2 * L, 64, 0, stream>>>(fp, fh, amh, amp, w2t, mtp, mth);
  gx_kernel<<<4 * (L / 8), 512, 0, stream>>>(mtp, mth, wih_f, wih_r, bih_f, bhh_f, bih_r, bhh_r, gx);
  lstm_kernel<<<4, 1024, 0, stream>>>(gx, whh_f, whh_r, out);
}